// Round 5
// baseline (808.875 us; speedup 1.0000x reference)
//
#include <hip/hip_runtime.h>
#include <hip/hip_bf16.h>
#include <stdint.h>

// DEQTrellisNetLM on MI355X (gfx950).
// B=4, L=1024, H=768, 4H=3072, NINP=512, K=2, NLAYER=10, NOUT=256.
//
//  - h time-major (B,L+1,H) bf16; c time-major (B,L+1,H) fp16. Row 0 = z0.
//  - Weights pre-permuted (N,K) bf16, gate-interleaved cols o'=(j>>4)*64+gate*16+(j&15).
//  - us precomputed once as fp16x4 gate-gathered: us4[m][j] = {i,o,g,f} (+ both biases).
//  - GEMM: 128x128 tile, BK=32, 4 waves, FRAGMENT-ORDERED LDS (each 16x32 MFMA
//    tile staged in exact lane order via per-lane gl_lds source -> ds_read_b128
//    at uniform_base + lane*16: zero bank conflicts, zero addr VALU),
//    3-deep pipeline with counted vmcnt(4) (T4), setprio (T5), XCD swizzle (T1).
//    Grid 768 = 3 blocks/CU (48KB LDS each) for inter-block latency hiding.

#define B_    4
#define L_    1024
#define LP1   1025
#define H_    768
#define NG_   3072
#define NINP_ 512
#define NOUT_ 256

typedef __bf16 bf16x8 __attribute__((ext_vector_type(8)));
typedef float f32x4 __attribute__((ext_vector_type(4)));
typedef _Float16 f16x4 __attribute__((ext_vector_type(4)));
using bf16_t = __hip_bfloat16;

__device__ __forceinline__ float sigf(float x){ return 1.f/(1.f + __expf(-x)); }
__device__ __forceinline__ float tanhf_(float x){
  float e = __expf(-2.f*fabsf(x));
  float r = (1.f - e)/(1.f + e);
  return x >= 0.f ? r : -r;
}

__device__ __forceinline__ void gl_lds16(const void* g, void* l){
  __builtin_amdgcn_global_load_lds(
    (const __attribute__((address_space(1))) uint32_t*)g,
    (__attribute__((address_space(3))) uint32_t*)l, 16, 0, 0);
}

// ---- init: zero Xt row0, set h/c row0 from z0 ----
__global__ void init_k(const float* __restrict__ z0, bf16_t* __restrict__ Xt,
                       bf16_t* __restrict__ Hb0, bf16_t* __restrict__ Hb1,
                       _Float16* __restrict__ Cb0, _Float16* __restrict__ Cb1){
  int tid = blockIdx.x*256 + threadIdx.x;
  if (tid < B_*NINP_){
    int b = tid >> 9, i = tid & 511;
    Xt[(size_t)b*LP1*NINP_ + i] = __float2bfloat16(0.f);
  }
  if (tid < B_*H_){
    int b = tid / H_, j = tid % H_;
    size_t idx = (size_t)b*LP1*H_ + j;
    bf16_t hz = __float2bfloat16(z0[b*2*H_ + j]);
    _Float16 cz = (_Float16)z0[b*2*H_ + H_ + j];
    Hb0[idx] = hz; Hb1[idx] = hz; Cb0[idx] = cz; Cb1[idx] = cz;
  }
}

// ---- weight prep: permute + transpose + bf16; biases gathered per-j float4 ----
__global__ void prep_w(const float* __restrict__ iw, const float* __restrict__ ib,
                       const float* __restrict__ cw, const float* __restrict__ cb,
                       bf16_t* __restrict__ Wit, bf16_t* __restrict__ Wct,
                       float* __restrict__ bias4){
  int op = blockIdx.x;
  int gate = (op >> 4) & 3;
  int j = ((op >> 6) << 4) | (op & 15);
  int o = gate*H_ + j;
  const float2* s2 = (const float2*)(iw + (size_t)o*NINP_*2);
  bf16_t* d = Wit + (size_t)op*(2*NINP_);
  for (int i = threadIdx.x; i < NINP_; i += 256){
    float2 v = s2[i];
    d[i]         = __float2bfloat16(v.x);   // tap k=0 (t-1)
    d[NINP_ + i] = __float2bfloat16(v.y);   // tap k=1 (t)
  }
  const float2* c2 = (const float2*)(cw + (size_t)o*H_*2);
  bf16_t* dc = Wct + (size_t)op*(2*H_);
  for (int i = threadIdx.x; i < H_; i += 256){
    float2 v = c2[i];
    dc[i]      = __float2bfloat16(v.x);
    dc[H_ + i] = __float2bfloat16(v.y);
  }
  if (threadIdx.x == 0) bias4[j*4 + gate] = ib[o] + cb[o];
}

// ---- X (B,512,1024) f32 -> Xt (B,1025,512) bf16, Xt[b][t+1][i] = X[b][i][t] ----
__global__ void transpose_x(const float* __restrict__ X, bf16_t* __restrict__ Xt){
  __shared__ float tile[64][65];
  int b = blockIdx.z;
  int t0 = blockIdx.x*64, i0 = blockIdx.y*64;
  int c = threadIdx.x & 63;
  for (int r = threadIdx.x >> 6; r < 64; r += 4)
    tile[r][c] = X[((size_t)b*NINP_ + i0 + r)*L_ + t0 + c];
  __syncthreads();
  for (int r = threadIdx.x >> 6; r < 64; r += 4)
    Xt[((size_t)b*LP1 + t0 + r + 1)*NINP_ + i0 + c] = __float2bfloat16(tile[c][r]);
}

// ---- 128^2 4-wave GEMM, fragment-ordered LDS, 3-deep counted-vmcnt pipeline ----
// MODE 0: us4 = f16x4 gather of A*Bt + bias   (A=Xt, K=1024)
// MODE 1: gates(A*Bt + us4) -> Hnew/Cnew      (A=Hprev, K=1536)
template<int KTOT, int AROW, int MODE>
__launch_bounds__(256, 3)
__global__ void gemmF(const bf16_t* __restrict__ A, const bf16_t* __restrict__ Bt,
                      const float* __restrict__ bias4, f16x4* __restrict__ us4,
                      const _Float16* __restrict__ Cprev, _Float16* __restrict__ Cnew,
                      bf16_t* __restrict__ Hnew, int bn_base){
  // 3 slots x (A 8KB + B 8KB); each 1KB sub-block = one 16x32 fragment tile
  __shared__ __align__(1024) char smem[49152];

  const int tid = threadIdx.x;
  const int l  = tid & 63;
  const int w  = tid >> 6;          // 0..3
  const int wm = w >> 1, wn = w & 1;
  const int lr = l & 15;            // row/col within fragment
  const int lk = l >> 4;            // 16B k-group (8 bf16)

  // XCD-bijective swizzle (nwg = 768 or 256, both % 8 == 0)
  const int nwg = gridDim.x * gridDim.y;
  int flat = blockIdx.y * gridDim.x + blockIdx.x;
  flat = (flat & 7) * (nwg >> 3) + (flat >> 3);
  const int bm0 = (flat & 31) * 128;           // gridDim.x == 32 (M blocks)
  const int bn0 = bn_base + (flat >> 5) * 128;

  f32x4 acc[4][4];
#pragma unroll
  for (int i = 0; i < 4; ++i)
#pragma unroll
    for (int jj = 0; jj < 4; ++jj)
      acc[i][jj] = (f32x4){0.f,0.f,0.f,0.f};

  // Staging: wave w owns A-frag-tiles {2w,2w+1} and B-frag-tiles {2w,2w+1}.
  // Per-lane global source = exact bytes lane l needs for MFMA:
  //   A: row bm0+mf*16+(l&15), k-bytes kt*64 + (l>>4)*16
  //   B: col bn0+nf*16+(l&15), same k-bytes      (Bt is (N,K) row-major)
  const char* ag[2]; const char* bg[2];
#pragma unroll
  for (int n = 0; n < 2; ++n){
    const int mf = w*2 + n;
    const int m = bm0 + mf*16 + lr;
    const int b = m >> 10, t = m & 1023;
    ag[n] = (const char*)A + (size_t)(b*LP1 + t)*(AROW*2) + lk*16;
    const int nc = bn0 + mf*16 + lr;
    bg[n] = (const char*)Bt + (size_t)nc*(KTOT*2) + lk*16;
  }
  const int a0off = (w*2    )*1024;
  const int a1off = (w*2 + 1)*1024;

#define STAGE_AT(S, KO) { \
    char* base_ = smem + (S)*16384; \
    gl_lds16(ag[0] + (KO), base_ + a0off); \
    gl_lds16(ag[1] + (KO), base_ + a1off); \
    gl_lds16(bg[0] + (KO), base_ + 8192 + a0off); \
    gl_lds16(bg[1] + (KO), base_ + 8192 + a1off); }

#define COMPUTE_AT(S) { \
    const char* sp_ = smem + (S)*16384 + l*16; \
    bf16x8 af[4], bv[4]; \
    _Pragma("unroll") for (int f = 0; f < 4; ++f) \
      af[f] = *(const bf16x8*)(sp_ + (wm*4 + f)*1024); \
    _Pragma("unroll") for (int f = 0; f < 4; ++f) \
      bv[f] = *(const bf16x8*)(sp_ + 8192 + (wn*4 + f)*1024); \
    __builtin_amdgcn_s_setprio(1); \
    _Pragma("unroll") for (int fm = 0; fm < 4; ++fm) \
      _Pragma("unroll") for (int fn = 0; fn < 4; ++fn) \
        acc[fm][fn] = __builtin_amdgcn_mfma_f32_16x16x32_bf16(af[fm], bv[fn], acc[fm][fn], 0, 0, 0); \
    __builtin_amdgcn_s_setprio(0); }

  constexpr int NT = KTOT / 32;

  STAGE_AT(0, 0)
  STAGE_AT(1, 64)
  int slot = 0;
  for (int t = 0; t < NT; ++t){
    if (t < NT - 1) { asm volatile("s_waitcnt vmcnt(4)" ::: "memory"); }
    else            { asm volatile("s_waitcnt vmcnt(0)" ::: "memory"); }
    __builtin_amdgcn_s_barrier();
    if (t + 2 < NT){
      const int s2 = (slot >= 1) ? slot - 1 : 2;   // (slot+2)%3
      STAGE_AT(s2, (t + 2) << 6)
    }
    COMPUTE_AT(slot)
    slot = (slot < 2) ? slot + 1 : 0;
  }

#undef STAGE_AT
#undef COMPUTE_AT

  const int jblk = (bn0 >> 6) + wn;
  const int j = jblk*16 + lr;
  const int rq = lk << 2;

  if (MODE == 0){
    const float4 bz = ((const float4*)bias4)[j];
#pragma unroll
    for (int fm = 0; fm < 4; ++fm){
      const int mbase = bm0 + wm*64 + fm*16 + rq;
#pragma unroll
      for (int r = 0; r < 4; ++r){
        const int m = mbase + r;
        f16x4 v = { (_Float16)(acc[fm][0][r] + bz.x), (_Float16)(acc[fm][1][r] + bz.y),
                    (_Float16)(acc[fm][2][r] + bz.z), (_Float16)(acc[fm][3][r] + bz.w) };
        us4[(size_t)m*H_ + j] = v;
      }
    }
  } else {
#pragma unroll
    for (int fm = 0; fm < 4; ++fm){
      const int mbase = bm0 + wm*64 + fm*16 + rq;
      f16x4 uv[4]; _Float16 cp16[4]; size_t hcb[4];
#pragma unroll
      for (int r = 0; r < 4; ++r){
        const int m = mbase + r;
        const int b = m >> 10, t = m & 1023;
        uv[r] = us4[(size_t)m*H_ + j];
        hcb[r] = (size_t)(b*LP1 + t)*H_ + j;
        cp16[r] = Cprev[hcb[r]];
      }
#pragma unroll
      for (int r = 0; r < 4; ++r){
        const float ig = acc[fm][0][r] + (float)uv[r][0];
        const float og = acc[fm][1][r] + (float)uv[r][1];
        const float gg = acc[fm][2][r] + (float)uv[r][2];
        const float fg = acc[fm][3][r] + (float)uv[r][3];
        const float c  = sigf(fg)*(float)cp16[r] + sigf(ig)*tanhf_(gg);
        const float h  = sigf(og)*tanhf_(c);
        Cnew[hcb[r] + H_] = (_Float16)c;          // row t+1
        Hnew[hcb[r] + H_] = __float2bfloat16(h);
      }
    }
  }
}

// ---- iteration 0: h=0 (c_prev=z0c at t=0) -> elementwise gates on us4 ----
__global__ void iter0_k(const f16x4* __restrict__ us4, bf16_t* __restrict__ Hn,
                        _Float16* __restrict__ Cn){
  const int m = blockIdx.y;
  const int j = blockIdx.x*256 + threadIdx.x;
  const int b = m >> 10, t = m & 1023;
  f16x4 u = us4[(size_t)m*H_ + j];
  const float ig = (float)u[0], og = (float)u[1], gg = (float)u[2], fg = (float)u[3];
  float cp = (t == 0) ? (float)Cn[(size_t)b*LP1*H_ + j] : 0.f;
  const float c = sigf(fg)*cp + sigf(ig)*tanhf_(gg);
  const float h = sigf(og)*tanhf_(c);
  const size_t idx = (size_t)(b*LP1 + t + 1)*H_ + j;
  Cn[idx] = (_Float16)c;
  Hn[idx] = __float2bfloat16(h);
}

// ---- tail: full-channel state at t=L for z0_out (reads it8 state) ----
__global__ void tail_k(const bf16_t* __restrict__ H8, const _Float16* __restrict__ C8,
                       const f16x4* __restrict__ us4, const bf16_t* __restrict__ Wct,
                       float* __restrict__ out){
  const int b = blockIdx.y;
  const int op = blockIdx.x*256 + threadIdx.x;
  const int gate = (op >> 4) & 3, lr = op & 15;
  const int j = ((op >> 6) << 4) | lr;
  const bf16_t* a  = H8 + (size_t)(b*LP1 + 1023)*H_;   // rows 1023,1024 = h8[1022],h8[1023]
  const bf16_t* wr = Wct + (size_t)op*1536;
  float s = 0.f;
#pragma unroll 4
  for (int k2 = 0; k2 < 1536; k2 += 8){
    bf16x8 av = *reinterpret_cast<const bf16x8*>(a + k2);
    bf16x8 wv = *reinterpret_cast<const bf16x8*>(wr + k2);
#pragma unroll
    for (int u = 0; u < 8; ++u) s += (float)av[u]*(float)wv[u];
  }
  s += (float)us4[(size_t)(b*1024 + 1023)*H_ + j][gate];
  const float si = __shfl(s, lr);
  const float so = __shfl(s, lr + 16);
  const float sg = __shfl(s, lr + 32);
  const float sf = __shfl(s, lr + 48);
  if (gate == 0){
    const float cp = (float)C8[(size_t)(b*LP1 + 1023)*H_ + j];  // c8 at time 1022
    const float c = sigf(sf)*cp + sigf(si)*tanhf_(sg);
    const float h = sigf(so)*tanhf_(c);
    out[B_*L_*NOUT_ + b*2*H_ + j]      = h;
    out[B_*L_*NOUT_ + b*2*H_ + H_ + j] = c;
  }
}

// ---- finalize: out (B,L,NOUT) from it9 h ----
__global__ void finalize_k(const bf16_t* __restrict__ Hf, float* __restrict__ out){
  const int tid = blockIdx.x*256 + threadIdx.x;
  const int n = tid & 255, t = (tid >> 8) & 1023, b = tid >> 18;
  out[tid] = __bfloat162float(Hf[((size_t)b*LP1 + t + 1)*H_ + (H_ - NOUT_) + n]);
}

extern "C" void kernel_launch(void* const* d_in, const int* in_sizes, int n_in,
                              void* d_out, int out_size, void* d_ws, size_t ws_size,
                              hipStream_t stream){
  const float* X   = (const float*)d_in[0];
  const float* z0  = (const float*)d_in[1];
  const float* iw  = (const float*)d_in[2];
  const float* ib  = (const float*)d_in[3];
  const float* cw  = (const float*)d_in[4];
  const float* cbv = (const float*)d_in[5];
  float* out = (float*)d_out;

  char* ws = (char*)d_ws;
  f16x4*    us4  = (f16x4*)   (ws + 0);           // 4096*768*8  = 25165824
  bf16_t*   Xt   = (bf16_t*)  (ws + 25165824);    // 4*1025*512*2 = 4198400
  bf16_t*   Wit  = (bf16_t*)  (ws + 29364224);    // 3072*1024*2 = 6291456
  bf16_t*   Wct  = (bf16_t*)  (ws + 35655680);    // 3072*1536*2 = 9437184
  float*    bias4= (float*)   (ws + 45092864);    // 768*4*4 = 12288
  bf16_t*   Hb0  = (bf16_t*)  (ws + 45105152);    // 4*1025*768*2 = 6297600
  bf16_t*   Hb1  = (bf16_t*)  (ws + 51402752);
  _Float16* Cb0  = (_Float16*)(ws + 57700352);    // 4*1025*768*2 = 6297600
  _Float16* Cb1  = (_Float16*)(ws + 63997952);    // end = 70295552 (~67MB)

  init_k<<<12, 256, 0, stream>>>(z0, Xt, Hb0, Hb1, Cb0, Cb1);
  prep_w<<<NG_, 256, 0, stream>>>(iw, ib, cw, cbv, Wit, Wct, bias4);
  transpose_x<<<dim3(L_/64, NINP_/64, B_), 256, 0, stream>>>(X, Xt);

  // inject conv as GEMM: M=4096, N=3072, K=1024 -> us4 (fp16, gate-gathered)
  gemmF<1024, NINP_, 0><<<dim3(32, 24), 256, 0, stream>>>(
      Xt, Wit, bias4, us4, nullptr, nullptr, nullptr, 0);

  // iteration 0 (h=0): elementwise on us4
  iter0_k<<<dim3(3, 4096), 256, 0, stream>>>(us4, Hb0, Cb0);

  // iterations 1..8: fused GEMM (K=1536) + gates, double-buffered
  bf16_t* Hp = Hb0; _Float16* Cp = Cb0;
  bf16_t* Hn = Hb1; _Float16* Cn = Cb1;
  for (int it = 1; it <= 8; ++it){
    gemmF<1536, H_, 1><<<dim3(32, 24), 256, 0, stream>>>(
        Hp, Wct, nullptr, us4, Cp, Cn, Hn, 0);
    bf16_t* th = Hp; Hp = Hn; Hn = th;
    _Float16* tc = Cp; Cp = Cn; Cn = tc;
  }

  // z0_out full-channel state at t=L (from it8 state), runs before reduced it9
  tail_k<<<dim3(12, B_), 256, 0, stream>>>(Hp, Cp, us4, Wct, out);

  // iteration 9: only o'-cols [2048,3072) (j in [512,768)) are needed for out
  gemmF<1536, H_, 1><<<dim3(32, 8), 256, 0, stream>>>(
      Hp, Wct, nullptr, us4, Cp, Cn, Hn, 2048);

  finalize_k<<<4096, 256, 0, stream>>>(Hn, out);
}

// Round 6
// 633.969 us; speedup vs baseline: 1.2759x; 1.2759x over previous
//
#include <hip/hip_runtime.h>
#include <hip/hip_bf16.h>
#include <stdint.h>

// DEQTrellisNetLM on MI355X (gfx950).
// B=4, L=1024, H=768, 4H=3072, NINP=512, K=2, NLAYER=10, NOUT=256.
//
//  - h time-major (B,L+1,H) bf16; c time-major (B,L+1,H) fp16. Row 0 = z0.
//  - Weights pre-permuted (N,K) bf16, gate-interleaved cols o'=(j>>4)*64+gate*16+(j&15).
//  - us precomputed once as fp16x4 gate-gathered (+ both biases), by MODE0 which
//    ALSO applies the first gate step (h=0) -> S1 in the same epilogue.
//  - GEMM: 128x128 tile, BK=32, 4 waves, 3-slot pipeline, counted vmcnt(4),
//    single s_barrier per K-step, setprio, XCD-bijective swizzle.
//  - LDS staging: 2-bit XOR chunk swizzle. Global source: lane l reads row l>>2,
//    chunk (l&3)^((l>>2)&3) -> 4 adjacent lanes cover one contiguous 64B row-chunk
//    (coalesced, R1's fetch behavior). LDS dest linear (lane*16, DMA requirement).
//    Fragment read: lr*64 + ((lk^(lr&3))<<4) -- bijection onto the 1KB tile's
//    16B quads => conflict-free (R3-verified class).
//  - MODE2 = last iteration, N-reduced to the NOUT range, writes out[] directly.

#define B_    4
#define L_    1024
#define LP1   1025
#define H_    768
#define NG_   3072
#define NINP_ 512
#define NOUT_ 256

typedef __bf16 bf16x8 __attribute__((ext_vector_type(8)));
typedef float f32x4 __attribute__((ext_vector_type(4)));
typedef _Float16 f16x4 __attribute__((ext_vector_type(4)));
using bf16_t = __hip_bfloat16;

__device__ __forceinline__ float sigf(float x){ return 1.f/(1.f + __expf(-x)); }
__device__ __forceinline__ float tanhf_(float x){
  float e = __expf(-2.f*fabsf(x));
  float r = (1.f - e)/(1.f + e);
  return x >= 0.f ? r : -r;
}

__device__ __forceinline__ void gl_lds16(const void* g, void* l){
  __builtin_amdgcn_global_load_lds(
    (const __attribute__((address_space(1))) uint32_t*)g,
    (__attribute__((address_space(3))) uint32_t*)l, 16, 0, 0);
}

// ---- init: zero Xt row0, set h/c row0 from z0 ----
__global__ void init_k(const float* __restrict__ z0, bf16_t* __restrict__ Xt,
                       bf16_t* __restrict__ Hb0, bf16_t* __restrict__ Hb1,
                       _Float16* __restrict__ Cb0, _Float16* __restrict__ Cb1){
  int tid = blockIdx.x*256 + threadIdx.x;
  if (tid < B_*NINP_){
    int b = tid >> 9, i = tid & 511;
    Xt[(size_t)b*LP1*NINP_ + i] = __float2bfloat16(0.f);
  }
  if (tid < B_*H_){
    int b = tid / H_, j = tid % H_;
    size_t idx = (size_t)b*LP1*H_ + j;
    bf16_t hz = __float2bfloat16(z0[b*2*H_ + j]);
    _Float16 cz = (_Float16)z0[b*2*H_ + H_ + j];
    Hb0[idx] = hz; Hb1[idx] = hz; Cb0[idx] = cz; Cb1[idx] = cz;
  }
}

// ---- weight prep: permute + transpose + bf16; biases gathered per-j float4 ----
__global__ void prep_w(const float* __restrict__ iw, const float* __restrict__ ib,
                       const float* __restrict__ cw, const float* __restrict__ cb,
                       bf16_t* __restrict__ Wit, bf16_t* __restrict__ Wct,
                       float* __restrict__ bias4){
  int op = blockIdx.x;
  int gate = (op >> 4) & 3;
  int j = ((op >> 6) << 4) | (op & 15);
  int o = gate*H_ + j;
  const float2* s2 = (const float2*)(iw + (size_t)o*NINP_*2);
  bf16_t* d = Wit + (size_t)op*(2*NINP_);
  for (int i = threadIdx.x; i < NINP_; i += 256){
    float2 v = s2[i];
    d[i]         = __float2bfloat16(v.x);   // tap k=0 (t-1)
    d[NINP_ + i] = __float2bfloat16(v.y);   // tap k=1 (t)
  }
  const float2* c2 = (const float2*)(cw + (size_t)o*H_*2);
  bf16_t* dc = Wct + (size_t)op*(2*H_);
  for (int i = threadIdx.x; i < H_; i += 256){
    float2 v = c2[i];
    dc[i]      = __float2bfloat16(v.x);
    dc[H_ + i] = __float2bfloat16(v.y);
  }
  if (threadIdx.x == 0) bias4[j*4 + gate] = ib[o] + cb[o];
}

// ---- X (B,512,1024) f32 -> Xt (B,1025,512) bf16, Xt[b][t+1][i] = X[b][i][t] ----
__global__ void transpose_x(const float* __restrict__ X, bf16_t* __restrict__ Xt){
  __shared__ float tile[64][65];
  int b = blockIdx.z;
  int t0 = blockIdx.x*64, i0 = blockIdx.y*64;
  int c = threadIdx.x & 63;
  for (int r = threadIdx.x >> 6; r < 64; r += 4)
    tile[r][c] = X[((size_t)b*NINP_ + i0 + r)*L_ + t0 + c];
  __syncthreads();
  for (int r = threadIdx.x >> 6; r < 64; r += 4)
    Xt[((size_t)b*LP1 + t0 + r + 1)*NINP_ + i0 + c] = __float2bfloat16(tile[c][r]);
}

// ---- 128^2 4-wave GEMM, XOR-swizzled frag-LDS, 3-slot counted-vmcnt pipeline ----
// MODE 0: us4 = gather(A*Bt + bias); ALSO first gate step (h=0) -> Hnew/Cnew row t+1
// MODE 1: gates(A*Bt + us4) -> Hnew/Cnew
// MODE 2: gates(A*Bt + us4) -> outF (B,L,NOUT) f32 directly (no state write)
template<int KTOT, int AROW, int MODE>
__launch_bounds__(256, 3)
__global__ void gemmF(const bf16_t* __restrict__ A, const bf16_t* __restrict__ Bt,
                      const float* __restrict__ bias4, f16x4* __restrict__ us4,
                      const _Float16* __restrict__ Cprev, _Float16* __restrict__ Cnew,
                      bf16_t* __restrict__ Hnew, float* __restrict__ outF, int bn_base){
  // 3 slots x (A 8KB + B 8KB); each 1KB sub-block = one 16x32 fragment tile
  __shared__ __align__(1024) char smem[49152];

  const int tid = threadIdx.x;
  const int l  = tid & 63;
  const int w  = tid >> 6;          // 0..3
  const int wm = w >> 1, wn = w & 1;
  const int lr = l & 15;            // row/col within fragment (read side)
  const int lk = l >> 4;            // k-group (read side)

  // XCD-bijective swizzle (nwg = 768 or 256, both % 8 == 0)
  const int nwg = gridDim.x * gridDim.y;
  int flat = blockIdx.y * gridDim.x + blockIdx.x;
  flat = (flat & 7) * (nwg >> 3) + (flat >> 3);
  const int bm0 = (flat & 31) * 128;           // gridDim.x == 32 (M blocks)
  const int bn0 = bn_base + (flat >> 5) * 128;

  f32x4 acc[4][4];
#pragma unroll
  for (int i = 0; i < 4; ++i)
#pragma unroll
    for (int jj = 0; jj < 4; ++jj)
      acc[i][jj] = (f32x4){0.f,0.f,0.f,0.f};

  // Staging (write side): lane l covers row rg = l>>2 of the fragment tile,
  // 16B chunk cg = (l&3)^(rg&3) within the row's 64B. Lanes 0-3 -> one
  // contiguous 64B global segment (coalesced). LDS dest = linear lane*16.
  const int rg = l >> 2;
  const int cg = (l & 3) ^ (rg & 3);
  const char* ag[2]; const char* bg[2];
#pragma unroll
  for (int n = 0; n < 2; ++n){
    const int mf = w*2 + n;
    const int m = bm0 + mf*16 + rg;
    const int b = m >> 10, t = m & 1023;
    ag[n] = (const char*)A + (size_t)(b*LP1 + t)*(AROW*2) + cg*16;
    const int nc = bn0 + mf*16 + rg;
    bg[n] = (const char*)Bt + (size_t)nc*(KTOT*2) + cg*16;
  }
  const int a0off = (w*2    )*1024;
  const int a1off = (w*2 + 1)*1024;

  // Read side: fragment f, lane l reads (row=lr, kgroup=lk) at the swizzled slot
  const int rdoff = lr*64 + ((lk ^ (lr & 3)) << 4);

#define STAGE_AT(S, KO) { \
    char* base_ = smem + (S)*16384; \
    gl_lds16(ag[0] + (KO), base_ + a0off); \
    gl_lds16(ag[1] + (KO), base_ + a1off); \
    gl_lds16(bg[0] + (KO), base_ + 8192 + a0off); \
    gl_lds16(bg[1] + (KO), base_ + 8192 + a1off); }

#define COMPUTE_AT(S) { \
    const char* sp_ = smem + (S)*16384 + rdoff; \
    bf16x8 af[4], bv[4]; \
    _Pragma("unroll") for (int f = 0; f < 4; ++f) \
      af[f] = *(const bf16x8*)(sp_ + (wm*4 + f)*1024); \
    _Pragma("unroll") for (int f = 0; f < 4; ++f) \
      bv[f] = *(const bf16x8*)(sp_ + 8192 + (wn*4 + f)*1024); \
    __builtin_amdgcn_s_setprio(1); \
    _Pragma("unroll") for (int fm = 0; fm < 4; ++fm) \
      _Pragma("unroll") for (int fn = 0; fn < 4; ++fn) \
        acc[fm][fn] = __builtin_amdgcn_mfma_f32_16x16x32_bf16(af[fm], bv[fn], acc[fm][fn], 0, 0, 0); \
    __builtin_amdgcn_s_setprio(0); }

  constexpr int NT = KTOT / 32;

  STAGE_AT(0, 0)
  STAGE_AT(1, 64)
  int slot = 0;
  for (int t = 0; t < NT; ++t){
    if (t < NT - 1) { asm volatile("s_waitcnt vmcnt(4)" ::: "memory"); }
    else            { asm volatile("s_waitcnt vmcnt(0)" ::: "memory"); }
    __builtin_amdgcn_s_barrier();
    if (t + 2 < NT){
      const int s2 = (slot >= 1) ? slot - 1 : 2;   // (slot+2)%3
      STAGE_AT(s2, (t + 2) << 6)
    }
    COMPUTE_AT(slot)
    slot = (slot < 2) ? slot + 1 : 0;
  }

#undef STAGE_AT
#undef COMPUTE_AT

  const int jblk = (bn0 >> 6) + wn;
  const int j = jblk*16 + lr;
  const int rq = lk << 2;

  if (MODE == 0){
    const float4 bz = ((const float4*)bias4)[j];
#pragma unroll
    for (int fm = 0; fm < 4; ++fm){
      const int mbase = bm0 + wm*64 + fm*16 + rq;
#pragma unroll
      for (int r = 0; r < 4; ++r){
        const int m = mbase + r;
        const int b = m >> 10, t = m & 1023;
        const float ig = acc[fm][0][r] + bz.x;
        const float og = acc[fm][1][r] + bz.y;
        const float gg = acc[fm][2][r] + bz.z;
        const float fg = acc[fm][3][r] + bz.w;
        us4[(size_t)m*H_ + j] = (f16x4){ (_Float16)ig, (_Float16)og,
                                         (_Float16)gg, (_Float16)fg };
        // fused first gate step (h_prev = 0; c_prev = z0c at t==0 else 0)
        const float cp = (t == 0) ? (float)Cprev[(size_t)b*LP1*H_ + j] : 0.f;
        const float c  = sigf(fg)*cp + sigf(ig)*tanhf_(gg);
        const float h  = sigf(og)*tanhf_(c);
        const size_t hcb = (size_t)(b*LP1 + t)*H_ + j;
        Cnew[hcb + H_] = (_Float16)c;
        Hnew[hcb + H_] = __float2bfloat16(h);
      }
    }
  } else {
    // batch-issue all epilogue operand loads, then do the gate math
    f16x4 uv[4][4]; _Float16 cp16[4][4];
#pragma unroll
    for (int fm = 0; fm < 4; ++fm){
      const int mbase = bm0 + wm*64 + fm*16 + rq;
#pragma unroll
      for (int r = 0; r < 4; ++r){
        const int m = mbase + r;
        const int b = m >> 10, t = m & 1023;
        uv[fm][r]  = us4[(size_t)m*H_ + j];
        cp16[fm][r] = Cprev[(size_t)(b*LP1 + t)*H_ + j];
      }
    }
#pragma unroll
    for (int fm = 0; fm < 4; ++fm){
      const int mbase = bm0 + wm*64 + fm*16 + rq;
#pragma unroll
      for (int r = 0; r < 4; ++r){
        const int m = mbase + r;
        const int b = m >> 10, t = m & 1023;
        const float ig = acc[fm][0][r] + (float)uv[fm][r][0];
        const float og = acc[fm][1][r] + (float)uv[fm][r][1];
        const float gg = acc[fm][2][r] + (float)uv[fm][r][2];
        const float fg = acc[fm][3][r] + (float)uv[fm][r][3];
        const float c  = sigf(fg)*(float)cp16[fm][r] + sigf(ig)*tanhf_(gg);
        const float h  = sigf(og)*tanhf_(c);
        if (MODE == 1){
          const size_t hcb = (size_t)(b*LP1 + t)*H_ + j;
          Cnew[hcb + H_] = (_Float16)c;
          Hnew[hcb + H_] = __float2bfloat16(h);
        } else {
          outF[(size_t)(b*1024 + t)*NOUT_ + (j - (H_ - NOUT_))] = h;
        }
      }
    }
  }
}

// ---- tail: full-channel state at t=L for z0_out (reads it8 state) ----
__global__ void tail_k(const bf16_t* __restrict__ H8, const _Float16* __restrict__ C8,
                       const f16x4* __restrict__ us4, const bf16_t* __restrict__ Wct,
                       float* __restrict__ out){
  const int b = blockIdx.y;
  const int op = blockIdx.x*256 + threadIdx.x;
  const int gate = (op >> 4) & 3, lr = op & 15;
  const int j = ((op >> 6) << 4) | lr;
  const bf16_t* a  = H8 + (size_t)(b*LP1 + 1023)*H_;   // rows 1023,1024 = h8[1022],h8[1023]
  const bf16_t* wr = Wct + (size_t)op*1536;
  float s = 0.f;
#pragma unroll 4
  for (int k2 = 0; k2 < 1536; k2 += 8){
    bf16x8 av = *reinterpret_cast<const bf16x8*>(a + k2);
    bf16x8 wv = *reinterpret_cast<const bf16x8*>(wr + k2);
#pragma unroll
    for (int u = 0; u < 8; ++u) s += (float)av[u]*(float)wv[u];
  }
  s += (float)us4[(size_t)(b*1024 + 1023)*H_ + j][gate];
  const float si = __shfl(s, lr);
  const float so = __shfl(s, lr + 16);
  const float sg = __shfl(s, lr + 32);
  const float sf = __shfl(s, lr + 48);
  if (gate == 0){
    const float cp = (float)C8[(size_t)(b*LP1 + 1023)*H_ + j];  // c8 at time 1022
    const float c = sigf(sf)*cp + sigf(si)*tanhf_(sg);
    const float h = sigf(so)*tanhf_(c);
    out[B_*L_*NOUT_ + b*2*H_ + j]      = h;
    out[B_*L_*NOUT_ + b*2*H_ + H_ + j] = c;
  }
}

extern "C" void kernel_launch(void* const* d_in, const int* in_sizes, int n_in,
                              void* d_out, int out_size, void* d_ws, size_t ws_size,
                              hipStream_t stream){
  const float* X   = (const float*)d_in[0];
  const float* z0  = (const float*)d_in[1];
  const float* iw  = (const float*)d_in[2];
  const float* ib  = (const float*)d_in[3];
  const float* cw  = (const float*)d_in[4];
  const float* cbv = (const float*)d_in[5];
  float* out = (float*)d_out;

  char* ws = (char*)d_ws;
  f16x4*    us4  = (f16x4*)   (ws + 0);           // 4096*768*8  = 25165824
  bf16_t*   Xt   = (bf16_t*)  (ws + 25165824);    // 4*1025*512*2 = 4198400
  bf16_t*   Wit  = (bf16_t*)  (ws + 29364224);    // 3072*1024*2 = 6291456
  bf16_t*   Wct  = (bf16_t*)  (ws + 35655680);    // 3072*1536*2 = 9437184
  float*    bias4= (float*)   (ws + 45092864);    // 768*4*4 = 12288
  bf16_t*   Hb0  = (bf16_t*)  (ws + 45105152);    // 4*1025*768*2 = 6297600
  bf16_t*   Hb1  = (bf16_t*)  (ws + 51402752);
  _Float16* Cb0  = (_Float16*)(ws + 57700352);    // 4*1025*768*2 = 6297600
  _Float16* Cb1  = (_Float16*)(ws + 63997952);    // end = 70295552 (~67MB)

  init_k<<<12, 256, 0, stream>>>(z0, Xt, Hb0, Hb1, Cb0, Cb1);
  prep_w<<<NG_, 256, 0, stream>>>(iw, ib, cw, cbv, Wit, Wct, bias4);
  transpose_x<<<dim3(L_/64, NINP_/64, B_), 256, 0, stream>>>(X, Xt);

  // inject GEMM (M=4096,N=3072,K=1024) -> us4, fused with first gate step -> S1
  gemmF<1024, NINP_, 0><<<dim3(32, 24), 256, 0, stream>>>(
      Xt, Wit, bias4, us4, Cb0, Cb0, Hb0, nullptr, 0);

  // iterations 2..9: fused GEMM (K=1536) + gates, double-buffered -> S9
  bf16_t* Hp = Hb0; _Float16* Cp = Cb0;
  bf16_t* Hn = Hb1; _Float16* Cn = Cb1;
  for (int it = 1; it <= 8; ++it){
    gemmF<1536, H_, 1><<<dim3(32, 24), 256, 0, stream>>>(
        Hp, Wct, nullptr, us4, Cp, Cn, Hn, nullptr, 0);
    bf16_t* th = Hp; Hp = Hn; Hn = th;
    _Float16* tc = Cp; Cp = Cn; Cn = tc;
  }

  // z0_out: full-channel state at t=L from S9 (computes step 10 at t=1023)
  tail_k<<<dim3(12, B_), 256, 0, stream>>>(Hp, Cp, us4, Wct, out);

  // step 10 (reduced N): only j in [512,768) needed -> writes out[] directly
  gemmF<1536, H_, 2><<<dim3(32, 8), 256, 0, stream>>>(
      Hp, Wct, nullptr, us4, Cp, nullptr, nullptr, out, 2048);
}

// Round 7
// 609.710 us; speedup vs baseline: 1.3267x; 1.0398x over previous
//
#include <hip/hip_runtime.h>
#include <hip/hip_bf16.h>
#include <stdint.h>

// DEQTrellisNetLM on MI355X (gfx950).
// B=4, L=1024, H=768, 4H=3072, NINP=512, K=2, NLAYER=10, NOUT=256.
//
// KEY LAYOUT: all GEMM operands stored FRAGMENT-TILE-MAJOR in global memory.
// A 16x32 MFMA tile = 1KB contiguous block, internal order = MFMA lane order
// (lane l = row (l&15), k-group (l>>4); 16B per lane). Staging reads
// tile_base + l*16 (perfect coalescing), global_load_lds writes LDS linearly,
// fragment reads are lane*16 (measured zero bank conflicts, R3/R5).
//  - A-operand (h / X) kept as TWO tiled copies: tap1 at t, tap0 at t+1
//    (so both taps of the K=2 conv are tile-aligned). Row (g=0,lr=0) of the
//    tap0 copy holds z0h / zeros.
//  - c time-major (B,L+1,H) fp16 (row 0 = z0c). us4 = fp16x4 gate-gathered.
//  - GEMM: 128x128 tile, BK=32, 4 waves, 3-slot LDS pipeline, counted vmcnt(4),
//    single s_barrier per K-step, setprio, XCD-bijective swizzle.
//  - MODE0 = inject GEMM + fused first gate step; MODE1 = middle iterations;
//    MODE2 = last iteration, N-reduced, writes out[] directly.

#define B_    4
#define L_    1024
#define LP1   1025
#define H_    768
#define NG_   3072
#define NINP_ 512
#define NOUT_ 256

typedef __bf16 bf16x8 __attribute__((ext_vector_type(8)));
typedef float f32x4 __attribute__((ext_vector_type(4)));
typedef _Float16 f16x4 __attribute__((ext_vector_type(4)));
using bf16_t = __hip_bfloat16;

__device__ __forceinline__ float sigf(float x){ return 1.f/(1.f + __expf(-x)); }
__device__ __forceinline__ float tanhf_(float x){
  float e = __expf(-2.f*fabsf(x));
  float r = (1.f - e)/(1.f + e);
  return x >= 0.f ? r : -r;
}

__device__ __forceinline__ void gl_lds16(const void* g, void* l){
  __builtin_amdgcn_global_load_lds(
    (const __attribute__((address_space(1))) uint32_t*)g,
    (__attribute__((address_space(3))) uint32_t*)l, 16, 0, 0);
}

// element index inside the H-tiled layout: [b][g=t>>4][kb=j>>5][512 elems]
__device__ __forceinline__ size_t htile_idx(int b, int t, int j){
  return ((size_t)((b*64 + (t>>4))*24) + (j>>5))*512
         + (size_t)((t&15)*8 + ((j>>3)&3)*128 + (j&7));
}

// ---- init: zero XB row (g0,lr0); z0h -> HB0/HB1 row (g0,lr0); z0c -> C rows 0 ----
__global__ void init_k(const float* __restrict__ z0, bf16_t* __restrict__ XB,
                       bf16_t* __restrict__ HB0, bf16_t* __restrict__ HB1,
                       _Float16* __restrict__ C0, _Float16* __restrict__ C1){
  int tid = blockIdx.x*256 + threadIdx.x;
  if (tid < B_*NINP_){
    int b = tid >> 9, r = tid & 511;
    int kb = r>>5, lk = (r>>3)&3, e = r&7;
    XB[((size_t)(b*64*16) + kb)*512 + lk*128 + e] = __float2bfloat16(0.f);
  }
  if (tid < B_*H_){
    int b = tid / H_, j = tid % H_;
    bf16_t hz = __float2bfloat16(z0[b*2*H_ + j]);
    _Float16 cz = (_Float16)z0[b*2*H_ + H_ + j];
    size_t a = ((size_t)(b*64*24) + (j>>5))*512 + ((j>>3)&3)*128 + (j&7);
    HB0[a] = hz; HB1[a] = hz;
    size_t idx = (size_t)b*LP1*H_ + j;
    C0[idx] = cz; C1[idx] = cz;
  }
}

// ---- weight prep: tile-major bf16 weights; biases gathered per-j float4 ----
__global__ void prep_w(const float* __restrict__ iw, const float* __restrict__ ib,
                       const float* __restrict__ cw, const float* __restrict__ cb,
                       bf16_t* __restrict__ WitT, bf16_t* __restrict__ WctT,
                       float* __restrict__ bias4){
  int op = blockIdx.x;
  int gate = (op >> 4) & 3;
  int j = ((op >> 6) << 4) | (op & 15);
  int o = gate*H_ + j;
  int nt = op >> 4, lrow = op & 15;
  const float2* s2 = (const float2*)(iw + (size_t)o*NINP_*2);
  for (int i = threadIdx.x; i < NINP_; i += 256){
    float2 v = s2[i];
    int k0 = i, k1 = NINP_ + i;
    WitT[((size_t)(nt*32 + (k0>>5)))*512 + lrow*8 + ((k0>>3)&3)*128 + (k0&7)] = __float2bfloat16(v.x);
    WitT[((size_t)(nt*32 + (k1>>5)))*512 + lrow*8 + ((k1>>3)&3)*128 + (k1&7)] = __float2bfloat16(v.y);
  }
  const float2* c2 = (const float2*)(cw + (size_t)o*H_*2);
  for (int i = threadIdx.x; i < H_; i += 256){
    float2 v = c2[i];
    int k0 = i, k1 = H_ + i;
    WctT[((size_t)(nt*48 + (k0>>5)))*512 + lrow*8 + ((k0>>3)&3)*128 + (k0&7)] = __float2bfloat16(v.x);
    WctT[((size_t)(nt*48 + (k1>>5)))*512 + lrow*8 + ((k1>>3)&3)*128 + (k1&7)] = __float2bfloat16(v.y);
  }
  if (threadIdx.x == 0) bias4[j*4 + gate] = ib[o] + cb[o];
}

// ---- X (B,512,1024) f32 -> XA (tap1, t) + XB (tap0, t+1) tiled bf16 ----
__global__ void tile_x(const float* __restrict__ X, bf16_t* __restrict__ XA,
                       bf16_t* __restrict__ XB){
  int b = blockIdx.z, i = blockIdx.y;
  int t = blockIdx.x*256 + threadIdx.x;
  bf16_t bv = __float2bfloat16(X[((size_t)b*NINP_ + i)*L_ + t]);
  int kb = i>>5, lk = (i>>3)&3, e = i&7;
  XA[((size_t)((b*64 + (t>>4))*16) + kb)*512 + (t&15)*8 + lk*128 + e] = bv;
  if (t < L_-1){
    int t1 = t + 1;
    XB[((size_t)((b*64 + (t1>>4))*16) + kb)*512 + (t1&15)*8 + lk*128 + e] = bv;
  }
}

// ---- 128^2 4-wave GEMM on tile-major operands, 3-slot counted-vmcnt pipeline ----
// MODE 0: us4 = gather(A*Bt + bias); fused first gate step (h=0) -> HA/HB/C
// MODE 1: gates(A*Bt + us4) -> HA/HB/C
// MODE 2: gates(A*Bt + us4) -> outF (B,L,NOUT) f32 directly
template<int KTOT, int MODE>
__launch_bounds__(256, 3)
__global__ void gemmF(const bf16_t* __restrict__ A1, const bf16_t* __restrict__ A0,
                      const bf16_t* __restrict__ Bt, const float* __restrict__ bias4,
                      f16x4* __restrict__ us4, const _Float16* __restrict__ Cprev,
                      _Float16* __restrict__ Cnew, bf16_t* __restrict__ HAn,
                      bf16_t* __restrict__ HBn, float* __restrict__ outF, int bn_base){
  // 3 slots x (A 8KB + B 8KB); each 1KB sub-block = one 16x32 fragment tile
  __shared__ __align__(1024) char smem[49152];

  const int tid = threadIdx.x;
  const int l  = tid & 63;
  const int w  = tid >> 6;          // 0..3
  const int wm = w >> 1, wn = w & 1;
  const int lr = l & 15;
  const int lk = l >> 4;

  // XCD-bijective swizzle (nwg = 768 or 256, both % 8 == 0)
  const int nwg = gridDim.x * gridDim.y;
  int flat = blockIdx.y * gridDim.x + blockIdx.x;
  flat = (flat & 7) * (nwg >> 3) + (flat >> 3);
  const int bm0 = (flat & 31) * 128;           // gridDim.x == 32 (M blocks)
  const int bn0 = bn_base + (flat >> 5) * 128;

  f32x4 acc[4][4];
#pragma unroll
  for (int i = 0; i < 4; ++i)
#pragma unroll
    for (int jj = 0; jj < 4; ++jj)
      acc[i][jj] = (f32x4){0.f,0.f,0.f,0.f};

  constexpr int KB0 = (KTOT == 1024) ? 16 : 24;   // tiles per tap per g
  constexpr int KBB = KTOT / 32;                  // B tiles per nt
  const int bI = bm0 >> 10;
  const int g0 = (bm0 >> 4) & 63;

  // per-wave tile base pointers (per-lane +l*16 folded in)
  const char* a0p[2]; const char* a1p[2]; const char* bp[2];
#pragma unroll
  for (int n = 0; n < 2; ++n){
    const int g = g0 + w*2 + n;
    a0p[n] = (const char*)A0 + (((size_t)(bI*64 + g)*KB0) << 10) + l*16;
    a1p[n] = (const char*)A1 + (((size_t)(bI*64 + g)*KB0) << 10) + l*16;
    const int nt = (bn0 >> 4) + w*2 + n;
    bp[n]  = (const char*)Bt + (((size_t)nt*KBB) << 10) + l*16;
  }
  const int a0off = (w*2    )*1024;
  const int a1off = (w*2 + 1)*1024;

#define STAGE_AT(S, T) { \
    char* base_ = smem + (S)*16384; \
    const int T_ = (T); \
    const size_t koA = (size_t)(T_ < KB0 ? T_ : T_ - KB0) << 10; \
    const char* as0 = (T_ < KB0) ? a0p[0] : a1p[0]; \
    const char* as1 = (T_ < KB0) ? a0p[1] : a1p[1]; \
    gl_lds16(as0 + koA, base_ + a0off); \
    gl_lds16(as1 + koA, base_ + a1off); \
    gl_lds16(bp[0] + ((size_t)T_ << 10), base_ + 8192 + a0off); \
    gl_lds16(bp[1] + ((size_t)T_ << 10), base_ + 8192 + a1off); }

#define COMPUTE_AT(S) { \
    const char* sp_ = smem + (S)*16384 + l*16; \
    bf16x8 af[4], bv[4]; \
    _Pragma("unroll") for (int f = 0; f < 4; ++f) \
      af[f] = *(const bf16x8*)(sp_ + (wm*4 + f)*1024); \
    _Pragma("unroll") for (int f = 0; f < 4; ++f) \
      bv[f] = *(const bf16x8*)(sp_ + 8192 + (wn*4 + f)*1024); \
    __builtin_amdgcn_s_setprio(1); \
    _Pragma("unroll") for (int fm = 0; fm < 4; ++fm) \
      _Pragma("unroll") for (int fn = 0; fn < 4; ++fn) \
        acc[fm][fn] = __builtin_amdgcn_mfma_f32_16x16x32_bf16(af[fm], bv[fn], acc[fm][fn], 0, 0, 0); \
    __builtin_amdgcn_s_setprio(0); }

  constexpr int NT = KTOT / 32;

  STAGE_AT(0, 0)
  STAGE_AT(1, 1)
  int slot = 0;
  for (int t = 0; t < NT; ++t){
    if (t < NT - 1) { asm volatile("s_waitcnt vmcnt(4)" ::: "memory"); }
    else            { asm volatile("s_waitcnt vmcnt(0)" ::: "memory"); }
    __builtin_amdgcn_s_barrier();
    if (t + 2 < NT){
      const int s2 = (slot >= 1) ? slot - 1 : 2;   // (slot+2)%3
      STAGE_AT(s2, t + 2)
    }
    COMPUTE_AT(slot)
    slot = (slot < 2) ? slot + 1 : 0;
  }

#undef STAGE_AT
#undef COMPUTE_AT

  const int jblk = (bn0 >> 6) + wn;
  const int j = jblk*16 + lr;
  const int rq = lk << 2;

  if (MODE == 0){
    const float4 bz = ((const float4*)bias4)[j];
#pragma unroll
    for (int fm = 0; fm < 4; ++fm){
      const int mbase = bm0 + wm*64 + fm*16 + rq;
#pragma unroll
      for (int r = 0; r < 4; ++r){
        const int m = mbase + r;
        const int b = m >> 10, t = m & 1023;
        const float ig = acc[fm][0][r] + bz.x;
        const float og = acc[fm][1][r] + bz.y;
        const float gg = acc[fm][2][r] + bz.z;
        const float fg = acc[fm][3][r] + bz.w;
        us4[(size_t)m*H_ + j] = (f16x4){ (_Float16)ig, (_Float16)og,
                                         (_Float16)gg, (_Float16)fg };
        const float cp = (t == 0) ? (float)Cprev[(size_t)b*LP1*H_ + j] : 0.f;
        const float c  = sigf(fg)*cp + sigf(ig)*tanhf_(gg);
        const float h  = sigf(og)*tanhf_(c);
        Cnew[(size_t)(b*LP1 + t + 1)*H_ + j] = (_Float16)c;
        bf16_t hb = __float2bfloat16(h);
        HAn[htile_idx(b, t, j)] = hb;
        if (t < L_-1) HBn[htile_idx(b, t+1, j)] = hb;
      }
    }
  } else {
    f16x4 uv[4][4]; _Float16 cp16[4][4];
#pragma unroll
    for (int fm = 0; fm < 4; ++fm){
      const int mbase = bm0 + wm*64 + fm*16 + rq;
#pragma unroll
      for (int r = 0; r < 4; ++r){
        const int m = mbase + r;
        const int b = m >> 10, t = m & 1023;
        uv[fm][r]   = us4[(size_t)m*H_ + j];
        cp16[fm][r] = Cprev[(size_t)(b*LP1 + t)*H_ + j];
      }
    }
#pragma unroll
    for (int fm = 0; fm < 4; ++fm){
      const int mbase = bm0 + wm*64 + fm*16 + rq;
#pragma unroll
      for (int r = 0; r < 4; ++r){
        const int m = mbase + r;
        const int b = m >> 10, t = m & 1023;
        const float ig = acc[fm][0][r] + (float)uv[fm][r][0];
        const float og = acc[fm][1][r] + (float)uv[fm][r][1];
        const float gg = acc[fm][2][r] + (float)uv[fm][r][2];
        const float fg = acc[fm][3][r] + (float)uv[fm][r][3];
        const float c  = sigf(fg)*(float)cp16[fm][r] + sigf(ig)*tanhf_(gg);
        const float h  = sigf(og)*tanhf_(c);
        if (MODE == 1){
          Cnew[(size_t)(b*LP1 + t + 1)*H_ + j] = (_Float16)c;
          bf16_t hb = __float2bfloat16(h);
          HAn[htile_idx(b, t, j)] = hb;
          if (t < L_-1) HBn[htile_idx(b, t+1, j)] = hb;
        } else {
          outF[(size_t)(b*1024 + t)*NOUT_ + (j - (H_ - NOUT_))] = h;
        }
      }
    }
  }
}

// ---- tail: full-channel state at t=L for z0_out (reads S9 tiled h) ----
__global__ void tail_k(const bf16_t* __restrict__ HA9, const bf16_t* __restrict__ HB9,
                       const _Float16* __restrict__ C9, const f16x4* __restrict__ us4,
                       const bf16_t* __restrict__ WctT, float* __restrict__ out){
  const int b = blockIdx.y;
  const int op = blockIdx.x*256 + threadIdx.x;
  const int gate = (op >> 4) & 3, lr = op & 15;
  const int j = ((op >> 6) << 4) | lr;
  const int nt = op >> 4;
  float s = 0.f;
  // g=63, lr=15 row of HB9 = h9[1022]; of HA9 = h9[1023]
  const size_t gbase = (size_t)(b*64 + 63) * 24;
#pragma unroll 4
  for (int kb = 0; kb < 48; ++kb){
    const bf16_t* hsrc = (kb < 24) ? HB9 + (gbase + kb)*512
                                   : HA9 + (gbase + (kb - 24))*512;
#pragma unroll
    for (int lkk = 0; lkk < 4; ++lkk){
      bf16x8 av = *reinterpret_cast<const bf16x8*>(hsrc + 120 + lkk*128);
      bf16x8 wv = *reinterpret_cast<const bf16x8*>(WctT + ((size_t)(nt*48 + kb))*512 + lr*8 + lkk*128);
#pragma unroll
      for (int u = 0; u < 8; ++u) s += (float)av[u]*(float)wv[u];
    }
  }
  s += (float)us4[(size_t)(b*1024 + 1023)*H_ + j][gate];
  const float si = __shfl(s, lr);
  const float so = __shfl(s, lr + 16);
  const float sg = __shfl(s, lr + 32);
  const float sf = __shfl(s, lr + 48);
  if (gate == 0){
    const float cp = (float)C9[(size_t)(b*LP1 + 1023)*H_ + j];  // c9 at time 1022
    const float c = sigf(sf)*cp + sigf(si)*tanhf_(sg);
    const float h = sigf(so)*tanhf_(c);
    out[B_*L_*NOUT_ + b*2*H_ + j]      = h;
    out[B_*L_*NOUT_ + b*2*H_ + H_ + j] = c;
  }
}

extern "C" void kernel_launch(void* const* d_in, const int* in_sizes, int n_in,
                              void* d_out, int out_size, void* d_ws, size_t ws_size,
                              hipStream_t stream){
  const float* X   = (const float*)d_in[0];
  const float* z0  = (const float*)d_in[1];
  const float* iw  = (const float*)d_in[2];
  const float* ib  = (const float*)d_in[3];
  const float* cw  = (const float*)d_in[4];
  const float* cbv = (const float*)d_in[5];
  float* out = (float*)d_out;

  char* ws = (char*)d_ws;
  f16x4*    us4  = (f16x4*)   (ws + 0);           // 4096*768*8  = 25165824
  bf16_t*   XA   = (bf16_t*)  (ws + 25165824);    // 4*64*16*512*2 = 4194304
  bf16_t*   XB   = (bf16_t*)  (ws + 29360128);    // 4194304
  bf16_t*   WitT = (bf16_t*)  (ws + 33554432);    // 192*32*512*2 = 6291456
  bf16_t*   WctT = (bf16_t*)  (ws + 39845888);    // 192*48*512*2 = 9437184
  float*    bias4= (float*)   (ws + 49283072);    // 12288
  bf16_t*   HA0  = (bf16_t*)  (ws + 49295360);    // 4*64*24*512*2 = 6291456
  bf16_t*   HB0  = (bf16_t*)  (ws + 55586816);
  bf16_t*   HA1  = (bf16_t*)  (ws + 61878272);
  bf16_t*   HB1  = (bf16_t*)  (ws + 68169728);
  _Float16* C0   = (_Float16*)(ws + 74461184);    // 4*1025*768*2 = 6297600
  _Float16* C1   = (_Float16*)(ws + 80758784);    // end = 87056384 (~83MB)

  init_k<<<12, 256, 0, stream>>>(z0, XB, HB0, HB1, C0, C1);
  prep_w<<<NG_, 256, 0, stream>>>(iw, ib, cw, cbv, WitT, WctT, bias4);
  tile_x<<<dim3(4, NINP_, B_), 256, 0, stream>>>(X, XA, XB);

  // inject GEMM (K=1024) -> us4, fused with first gate step -> S1 (HA0/HB0/C0)
  gemmF<1024, 0><<<dim3(32, 24), 256, 0, stream>>>(
      XA, XB, WitT, bias4, us4, C0, C0, HA0, HB0, nullptr, 0);

  // iterations 2..9: fused GEMM (K=1536) + gates, double-buffered -> S9
  bf16_t* HAp = HA0; bf16_t* HBp = HB0; _Float16* Cp = C0;
  bf16_t* HAn = HA1; bf16_t* HBn = HB1; _Float16* Cn = C1;
  for (int it = 1; it <= 8; ++it){
    gemmF<1536, 1><<<dim3(32, 24), 256, 0, stream>>>(
        HAp, HBp, WctT, nullptr, us4, Cp, Cn, HAn, HBn, nullptr, 0);
    bf16_t* ta = HAp; HAp = HAn; HAn = ta;
    bf16_t* tb = HBp; HBp = HBn; HBn = tb;
    _Float16* tc = Cp; Cp = Cn; Cn = tc;
  }

  // z0_out: step 10 at t=1023, full channels, from S9
  tail_k<<<dim3(12, B_), 256, 0, stream>>>(HAp, HBp, Cp, us4, WctT, out);

  // step 10 (reduced N): j in [512,768) -> writes out[] directly
  gemmF<1536, 2><<<dim3(32, 8), 256, 0, stream>>>(
      HAp, HBp, WctT, nullptr, us4, Cp, nullptr, nullptr, nullptr, out, 2048);
}

// Round 8
// 570.819 us; speedup vs baseline: 1.4170x; 1.0681x over previous
//
#include <hip/hip_runtime.h>
#include <hip/hip_bf16.h>
#include <stdint.h>

// DEQTrellisNetLM on MI355X (gfx950).
// B=4, L=1024, H=768, 4H=3072, NINP=512, K=2, NLAYER=10, NOUT=256.
//
// KEY LAYOUT: all GEMM operands stored FRAGMENT-TILE-MAJOR in global memory.
// A 16x32 MFMA tile = 1KB contiguous block, internal order = MFMA lane order
// (lane l = row (l&15), k-group (l>>4); 16B per lane). Staging reads
// tile_base + l*16 (perfect coalescing), global_load_lds writes LDS linearly,
// fragment reads are lane*16 (measured zero bank conflicts, R3/R5).
//  - A-operand (h / X) kept as TWO tiled copies: tap1 at t, tap0 at t+1.
//  - c time-major (B,L+1,H) fp16 (row 0 = z0c). us4 = fp16x4 gate-gathered.
//  - GEMM: 128x128 tile, BK=32, 4 waves, 3-slot LDS pipeline, counted vmcnt(4),
//    single s_barrier per K-step, setprio, XCD-bijective swizzle.
//  - MODE0 = inject GEMM + fused first gate step; MODE1 = middle iterations;
//    MODE2 = last iteration, N-reduced, writes out[] directly.
//  - tail_k (z0_out): K-split 4-way + LDS reduce, 192 blocks (was 48 serial
//    blocks at 70us / 1.8% occupancy).

#define B_    4
#define L_    1024
#define LP1   1025
#define H_    768
#define NG_   3072
#define NINP_ 512
#define NOUT_ 256

typedef __bf16 bf16x8 __attribute__((ext_vector_type(8)));
typedef float f32x4 __attribute__((ext_vector_type(4)));
typedef _Float16 f16x4 __attribute__((ext_vector_type(4)));
using bf16_t = __hip_bfloat16;

__device__ __forceinline__ float sigf(float x){ return 1.f/(1.f + __expf(-x)); }
__device__ __forceinline__ float tanhf_(float x){
  float e = __expf(-2.f*fabsf(x));
  float r = (1.f - e)/(1.f + e);
  return x >= 0.f ? r : -r;
}

__device__ __forceinline__ void gl_lds16(const void* g, void* l){
  __builtin_amdgcn_global_load_lds(
    (const __attribute__((address_space(1))) uint32_t*)g,
    (__attribute__((address_space(3))) uint32_t*)l, 16, 0, 0);
}

// element index inside the H-tiled layout: [b][g=t>>4][kb=j>>5][512 elems]
__device__ __forceinline__ size_t htile_idx(int b, int t, int j){
  return ((size_t)((b*64 + (t>>4))*24) + (j>>5))*512
         + (size_t)((t&15)*8 + ((j>>3)&3)*128 + (j&7));
}

// ---- init: zero XB row (g0,lr0); z0h -> HB0/HB1 row (g0,lr0); z0c -> C rows 0 ----
__global__ void init_k(const float* __restrict__ z0, bf16_t* __restrict__ XB,
                       bf16_t* __restrict__ HB0, bf16_t* __restrict__ HB1,
                       _Float16* __restrict__ C0, _Float16* __restrict__ C1){
  int tid = blockIdx.x*256 + threadIdx.x;
  if (tid < B_*NINP_){
    int b = tid >> 9, r = tid & 511;
    int kb = r>>5, lk = (r>>3)&3, e = r&7;
    XB[((size_t)(b*64*16) + kb)*512 + lk*128 + e] = __float2bfloat16(0.f);
  }
  if (tid < B_*H_){
    int b = tid / H_, j = tid % H_;
    bf16_t hz = __float2bfloat16(z0[b*2*H_ + j]);
    _Float16 cz = (_Float16)z0[b*2*H_ + H_ + j];
    size_t a = ((size_t)(b*64*24) + (j>>5))*512 + ((j>>3)&3)*128 + (j&7);
    HB0[a] = hz; HB1[a] = hz;
    size_t idx = (size_t)b*LP1*H_ + j;
    C0[idx] = cz; C1[idx] = cz;
  }
}

// ---- weight prep: tile-major bf16 weights; biases gathered per-j float4 ----
__global__ void prep_w(const float* __restrict__ iw, const float* __restrict__ ib,
                       const float* __restrict__ cw, const float* __restrict__ cb,
                       bf16_t* __restrict__ WitT, bf16_t* __restrict__ WctT,
                       float* __restrict__ bias4){
  int op = blockIdx.x;
  int gate = (op >> 4) & 3;
  int j = ((op >> 6) << 4) | (op & 15);
  int o = gate*H_ + j;
  int nt = op >> 4, lrow = op & 15;
  const float2* s2 = (const float2*)(iw + (size_t)o*NINP_*2);
  for (int i = threadIdx.x; i < NINP_; i += 256){
    float2 v = s2[i];
    int k0 = i, k1 = NINP_ + i;
    WitT[((size_t)(nt*32 + (k0>>5)))*512 + lrow*8 + ((k0>>3)&3)*128 + (k0&7)] = __float2bfloat16(v.x);
    WitT[((size_t)(nt*32 + (k1>>5)))*512 + lrow*8 + ((k1>>3)&3)*128 + (k1&7)] = __float2bfloat16(v.y);
  }
  const float2* c2 = (const float2*)(cw + (size_t)o*H_*2);
  for (int i = threadIdx.x; i < H_; i += 256){
    float2 v = c2[i];
    int k0 = i, k1 = H_ + i;
    WctT[((size_t)(nt*48 + (k0>>5)))*512 + lrow*8 + ((k0>>3)&3)*128 + (k0&7)] = __float2bfloat16(v.x);
    WctT[((size_t)(nt*48 + (k1>>5)))*512 + lrow*8 + ((k1>>3)&3)*128 + (k1&7)] = __float2bfloat16(v.y);
  }
  if (threadIdx.x == 0) bias4[j*4 + gate] = ib[o] + cb[o];
}

// ---- X (B,512,1024) f32 -> XA (tap1, t) + XB (tap0, t+1) tiled bf16 ----
__global__ void tile_x(const float* __restrict__ X, bf16_t* __restrict__ XA,
                       bf16_t* __restrict__ XB){
  int b = blockIdx.z, i = blockIdx.y;
  int t = blockIdx.x*256 + threadIdx.x;
  bf16_t bv = __float2bfloat16(X[((size_t)b*NINP_ + i)*L_ + t]);
  int kb = i>>5, lk = (i>>3)&3, e = i&7;
  XA[((size_t)((b*64 + (t>>4))*16) + kb)*512 + (t&15)*8 + lk*128 + e] = bv;
  if (t < L_-1){
    int t1 = t + 1;
    XB[((size_t)((b*64 + (t1>>4))*16) + kb)*512 + (t1&15)*8 + lk*128 + e] = bv;
  }
}

// ---- 128^2 4-wave GEMM on tile-major operands, 3-slot counted-vmcnt pipeline ----
// MODE 0: us4 = gather(A*Bt + bias); fused first gate step (h=0) -> HA/HB/C
// MODE 1: gates(A*Bt + us4) -> HA/HB/C
// MODE 2: gates(A*Bt + us4) -> outF (B,L,NOUT) f32 directly
template<int KTOT, int MODE>
__launch_bounds__(256, 3)
__global__ void gemmF(const bf16_t* __restrict__ A1, const bf16_t* __restrict__ A0,
                      const bf16_t* __restrict__ Bt, const float* __restrict__ bias4,
                      f16x4* __restrict__ us4, const _Float16* __restrict__ Cprev,
                      _Float16* __restrict__ Cnew, bf16_t* __restrict__ HAn,
                      bf16_t* __restrict__ HBn, float* __restrict__ outF, int bn_base){
  // 3 slots x (A 8KB + B 8KB); each 1KB sub-block = one 16x32 fragment tile
  __shared__ __align__(1024) char smem[49152];

  const int tid = threadIdx.x;
  const int l  = tid & 63;
  const int w  = tid >> 6;          // 0..3
  const int wm = w >> 1, wn = w & 1;
  const int lr = l & 15;
  const int lk = l >> 4;

  // XCD-bijective swizzle (nwg = 768 or 256, both % 8 == 0)
  const int nwg = gridDim.x * gridDim.y;
  int flat = blockIdx.y * gridDim.x + blockIdx.x;
  flat = (flat & 7) * (nwg >> 3) + (flat >> 3);
  const int bm0 = (flat & 31) * 128;           // gridDim.x == 32 (M blocks)
  const int bn0 = bn_base + (flat >> 5) * 128;

  f32x4 acc[4][4];
#pragma unroll
  for (int i = 0; i < 4; ++i)
#pragma unroll
    for (int jj = 0; jj < 4; ++jj)
      acc[i][jj] = (f32x4){0.f,0.f,0.f,0.f};

  constexpr int KB0 = (KTOT == 1024) ? 16 : 24;   // tiles per tap per g
  constexpr int KBB = KTOT / 32;                  // B tiles per nt
  const int bI = bm0 >> 10;
  const int g0 = (bm0 >> 4) & 63;

  // per-wave tile base pointers (per-lane +l*16 folded in)
  const char* a0p[2]; const char* a1p[2]; const char* bp[2];
#pragma unroll
  for (int n = 0; n < 2; ++n){
    const int g = g0 + w*2 + n;
    a0p[n] = (const char*)A0 + (((size_t)(bI*64 + g)*KB0) << 10) + l*16;
    a1p[n] = (const char*)A1 + (((size_t)(bI*64 + g)*KB0) << 10) + l*16;
    const int nt = (bn0 >> 4) + w*2 + n;
    bp[n]  = (const char*)Bt + (((size_t)nt*KBB) << 10) + l*16;
  }
  const int a0off = (w*2    )*1024;
  const int a1off = (w*2 + 1)*1024;

#define STAGE_AT(S, T) { \
    char* base_ = smem + (S)*16384; \
    const int T_ = (T); \
    const size_t koA = (size_t)(T_ < KB0 ? T_ : T_ - KB0) << 10; \
    const char* as0 = (T_ < KB0) ? a0p[0] : a1p[0]; \
    const char* as1 = (T_ < KB0) ? a0p[1] : a1p[1]; \
    gl_lds16(as0 + koA, base_ + a0off); \
    gl_lds16(as1 + koA, base_ + a1off); \
    gl_lds16(bp[0] + ((size_t)T_ << 10), base_ + 8192 + a0off); \
    gl_lds16(bp[1] + ((size_t)T_ << 10), base_ + 8192 + a1off); }

#define COMPUTE_AT(S) { \
    const char* sp_ = smem + (S)*16384 + l*16; \
    bf16x8 af[4], bv[4]; \
    _Pragma("unroll") for (int f = 0; f < 4; ++f) \
      af[f] = *(const bf16x8*)(sp_ + (wm*4 + f)*1024); \
    _Pragma("unroll") for (int f = 0; f < 4; ++f) \
      bv[f] = *(const bf16x8*)(sp_ + 8192 + (wn*4 + f)*1024); \
    __builtin_amdgcn_s_setprio(1); \
    _Pragma("unroll") for (int fm = 0; fm < 4; ++fm) \
      _Pragma("unroll") for (int fn = 0; fn < 4; ++fn) \
        acc[fm][fn] = __builtin_amdgcn_mfma_f32_16x16x32_bf16(af[fm], bv[fn], acc[fm][fn], 0, 0, 0); \
    __builtin_amdgcn_s_setprio(0); }

  constexpr int NT = KTOT / 32;

  STAGE_AT(0, 0)
  STAGE_AT(1, 1)
  int slot = 0;
  for (int t = 0; t < NT; ++t){
    if (t < NT - 1) { asm volatile("s_waitcnt vmcnt(4)" ::: "memory"); }
    else            { asm volatile("s_waitcnt vmcnt(0)" ::: "memory"); }
    __builtin_amdgcn_s_barrier();
    if (t + 2 < NT){
      const int s2 = (slot >= 1) ? slot - 1 : 2;   // (slot+2)%3
      STAGE_AT(s2, t + 2)
    }
    COMPUTE_AT(slot)
    slot = (slot < 2) ? slot + 1 : 0;
  }

#undef STAGE_AT
#undef COMPUTE_AT

  const int jblk = (bn0 >> 6) + wn;
  const int j = jblk*16 + lr;
  const int rq = lk << 2;

  if (MODE == 0){
    const float4 bz = ((const float4*)bias4)[j];
#pragma unroll
    for (int fm = 0; fm < 4; ++fm){
      const int mbase = bm0 + wm*64 + fm*16 + rq;
#pragma unroll
      for (int r = 0; r < 4; ++r){
        const int m = mbase + r;
        const int b = m >> 10, t = m & 1023;
        const float ig = acc[fm][0][r] + bz.x;
        const float og = acc[fm][1][r] + bz.y;
        const float gg = acc[fm][2][r] + bz.z;
        const float fg = acc[fm][3][r] + bz.w;
        us4[(size_t)m*H_ + j] = (f16x4){ (_Float16)ig, (_Float16)og,
                                         (_Float16)gg, (_Float16)fg };
        const float cp = (t == 0) ? (float)Cprev[(size_t)b*LP1*H_ + j] : 0.f;
        const float c  = sigf(fg)*cp + sigf(ig)*tanhf_(gg);
        const float h  = sigf(og)*tanhf_(c);
        Cnew[(size_t)(b*LP1 + t + 1)*H_ + j] = (_Float16)c;
        bf16_t hb = __float2bfloat16(h);
        HAn[htile_idx(b, t, j)] = hb;
        if (t < L_-1) HBn[htile_idx(b, t+1, j)] = hb;
      }
    }
  } else {
    f16x4 uv[4][4]; _Float16 cp16[4][4];
#pragma unroll
    for (int fm = 0; fm < 4; ++fm){
      const int mbase = bm0 + wm*64 + fm*16 + rq;
#pragma unroll
      for (int r = 0; r < 4; ++r){
        const int m = mbase + r;
        const int b = m >> 10, t = m & 1023;
        uv[fm][r]   = us4[(size_t)m*H_ + j];
        cp16[fm][r] = Cprev[(size_t)(b*LP1 + t)*H_ + j];
      }
    }
#pragma unroll
    for (int fm = 0; fm < 4; ++fm){
      const int mbase = bm0 + wm*64 + fm*16 + rq;
#pragma unroll
      for (int r = 0; r < 4; ++r){
        const int m = mbase + r;
        const int b = m >> 10, t = m & 1023;
        const float ig = acc[fm][0][r] + (float)uv[fm][r][0];
        const float og = acc[fm][1][r] + (float)uv[fm][r][1];
        const float gg = acc[fm][2][r] + (float)uv[fm][r][2];
        const float fg = acc[fm][3][r] + (float)uv[fm][r][3];
        const float c  = sigf(fg)*(float)cp16[fm][r] + sigf(ig)*tanhf_(gg);
        const float h  = sigf(og)*tanhf_(c);
        if (MODE == 1){
          Cnew[(size_t)(b*LP1 + t + 1)*H_ + j] = (_Float16)c;
          bf16_t hb = __float2bfloat16(h);
          HAn[htile_idx(b, t, j)] = hb;
          if (t < L_-1) HBn[htile_idx(b, t+1, j)] = hb;
        } else {
          outF[(size_t)(b*1024 + t)*NOUT_ + (j - (H_ - NOUT_))] = h;
        }
      }
    }
  }
}

// ---- tail: full-channel state at t=L for z0_out, K-split 4-way ----
// grid (48, B), 256 thr: thread (opl = t&63, q = t>>6) sums k in [q*384, q*384+384)
// of op = blockIdx.x*64 + opl; LDS reduce; wave 0 does gates + write.
__global__ void tail_k(const bf16_t* __restrict__ HA9, const bf16_t* __restrict__ HB9,
                       const _Float16* __restrict__ C9, const f16x4* __restrict__ us4,
                       const bf16_t* __restrict__ WctT, float* __restrict__ out){
  __shared__ float red[4][64];
  const int b = blockIdx.y;
  const int ob = blockIdx.x;
  const int opl = threadIdx.x & 63;
  const int q   = threadIdx.x >> 6;
  const int nt = ob*4 + (opl >> 4);
  const int lr = opl & 15;

  // k-range [q*384, (q+1)*384): q<2 -> tap0 (HB9, j=k), q>=2 -> tap1 (HA9, j=k-768)
  const bf16_t* hsrcb = (q < 2) ? HB9 : HA9;
  const int j0q = (q < 2) ? q*384 : (q-2)*384;          // j offset of this quarter
  const size_t gbase = (size_t)(b*64 + 63) * 24;
  const bf16_t* wbase = WctT + ((size_t)(nt*48 + ((q*384)>>5)))*512 + lr*8;

  float s = 0.f;
#pragma unroll 4
  for (int i = 0; i < 48; ++i){                          // 8 k-elems per iter
    const int koff = i*8;                                // within-quarter k offset
    const int j = j0q + koff;
    bf16x8 wv = *reinterpret_cast<const bf16x8*>(wbase + (koff>>5)*512 + ((koff>>3)&3)*128);
    bf16x8 hv = *reinterpret_cast<const bf16x8*>(hsrcb + (gbase + (j>>5))*512 + 120 + ((j>>3)&3)*128);
#pragma unroll
    for (int u = 0; u < 8; ++u) s += (float)hv[u]*(float)wv[u];
  }
  red[q][opl] = s;
  __syncthreads();
  if (threadIdx.x < 64){
    const int gate = (opl >> 4) & 3;
    const int j = ob*16 + lr;
    float sv = red[0][opl] + red[1][opl] + red[2][opl] + red[3][opl];
    sv += (float)us4[(size_t)(b*1024 + 1023)*H_ + j][gate];
    const float si = __shfl(sv, lr);
    const float so = __shfl(sv, lr + 16);
    const float sg = __shfl(sv, lr + 32);
    const float sf = __shfl(sv, lr + 48);
    if (gate == 0){
      const float cp = (float)C9[(size_t)(b*LP1 + 1023)*H_ + j];  // c9 at time 1022
      const float c = sigf(sf)*cp + sigf(si)*tanhf_(sg);
      const float h = sigf(so)*tanhf_(c);
      out[B_*L_*NOUT_ + b*2*H_ + j]      = h;
      out[B_*L_*NOUT_ + b*2*H_ + H_ + j] = c;
    }
  }
}

extern "C" void kernel_launch(void* const* d_in, const int* in_sizes, int n_in,
                              void* d_out, int out_size, void* d_ws, size_t ws_size,
                              hipStream_t stream){
  const float* X   = (const float*)d_in[0];
  const float* z0  = (const float*)d_in[1];
  const float* iw  = (const float*)d_in[2];
  const float* ib  = (const float*)d_in[3];
  const float* cw  = (const float*)d_in[4];
  const float* cbv = (const float*)d_in[5];
  float* out = (float*)d_out;

  char* ws = (char*)d_ws;
  f16x4*    us4  = (f16x4*)   (ws + 0);           // 4096*768*8  = 25165824
  bf16_t*   XA   = (bf16_t*)  (ws + 25165824);    // 4*64*16*512*2 = 4194304
  bf16_t*   XB   = (bf16_t*)  (ws + 29360128);    // 4194304
  bf16_t*   WitT = (bf16_t*)  (ws + 33554432);    // 192*32*512*2 = 6291456
  bf16_t*   WctT = (bf16_t*)  (ws + 39845888);    // 192*48*512*2 = 9437184
  float*    bias4= (float*)   (ws + 49283072);    // 12288
  bf16_t*   HA0  = (bf16_t*)  (ws + 49295360);    // 4*64*24*512*2 = 6291456
  bf16_t*   HB0  = (bf16_t*)  (ws + 55586816);
  bf16_t*   HA1  = (bf16_t*)  (ws + 61878272);
  bf16_t*   HB1  = (bf16_t*)  (ws + 68169728);
  _Float16* C0   = (_Float16*)(ws + 74461184);    // 4*1025*768*2 = 6297600
  _Float16* C1   = (_Float16*)(ws + 80758784);    // end = 87056384 (~83MB)

  init_k<<<12, 256, 0, stream>>>(z0, XB, HB0, HB1, C0, C1);
  prep_w<<<NG_, 256, 0, stream>>>(iw, ib, cw, cbv, WitT, WctT, bias4);
  tile_x<<<dim3(4, NINP_, B_), 256, 0, stream>>>(X, XA, XB);

  // inject GEMM (K=1024) -> us4, fused with first gate step -> S1 (HA0/HB0/C0)
  gemmF<1024, 0><<<dim3(32, 24), 256, 0, stream>>>(
      XA, XB, WitT, bias4, us4, C0, C0, HA0, HB0, nullptr, 0);

  // iterations 2..9: fused GEMM (K=1536) + gates, double-buffered -> S9
  bf16_t* HAp = HA0; bf16_t* HBp = HB0; _Float16* Cp = C0;
  bf16_t* HAn = HA1; bf16_t* HBn = HB1; _Float16* Cn = C1;
  for (int it = 1; it <= 8; ++it){
    gemmF<1536, 1><<<dim3(32, 24), 256, 0, stream>>>(
        HAp, HBp, WctT, nullptr, us4, Cp, Cn, HAn, HBn, nullptr, 0);
    bf16_t* ta = HAp; HAp = HAn; HAn = ta;
    bf16_t* tb = HBp; HBp = HBn; HBn = tb;
    _Float16* tc = Cp; Cp = Cn; Cn = tc;
  }

  // z0_out: step 10 at t=1023, full channels, from S9
  tail_k<<<dim3(48, B_), 256, 0, stream>>>(HAp, HBp, Cp, us4, WctT, out);

  // step 10 (reduced N): j in [512,768) -> writes out[] directly
  gemmF<1536, 2><<<dim3(32, 8), 256, 0, stream>>>(
      HAp, HBp, WctT, nullptr, us4, Cp, nullptr, nullptr, nullptr, out, 2048);
}